// Round 4
// baseline (489.361 us; speedup 1.0000x reference)
//
#include <hip/hip_runtime.h>

typedef _Float16 f16;
typedef unsigned int uint;
typedef f16 f16x2 __attribute__((ext_vector_type(2)));
typedef f16 f16x8 __attribute__((ext_vector_type(8)));
typedef __fp16 h16x2 __attribute__((ext_vector_type(2)));
typedef float f32x4 __attribute__((ext_vector_type(4)));

#define Bn 512
#define Ln 128
#define Dn 128
#define Cn 512   // 4 gates * D

__device__ __forceinline__ float fdot2f(uint a, uint b, float c) {
#if __has_builtin(__builtin_amdgcn_fdot2)
  return __builtin_amdgcn_fdot2(__builtin_bit_cast(f16x2, a),
                                __builtin_bit_cast(f16x2, b), c, false);
#else
  f16x2 av = __builtin_bit_cast(f16x2, a), bv = __builtin_bit_cast(f16x2, b);
  return c + (float)av[0] * (float)bv[0] + (float)av[1] * (float)bv[1];
#endif
}

__device__ __forceinline__ uint pk2(float a, float b) {
#if __has_builtin(__builtin_amdgcn_cvt_pkrtz)
  h16x2 v = __builtin_amdgcn_cvt_pkrtz(a, b);
  return __builtin_bit_cast(uint, v);
#else
  f16x2 v; v[0] = (f16)a; v[1] = (f16)b;
  return __builtin_bit_cast(uint, v);
#endif
}

// ---------------- fused embedding gather + layernorm(layer0) ----------------
// writes x (f32 residual base) and xn (f16 normalized)
__global__ __launch_bounds__(256) void k_embed_ln(const int* __restrict__ ids,
                                                  const float* __restrict__ emb,
                                                  const float* __restrict__ lw,
                                                  const float* __restrict__ lb,
                                                  float* __restrict__ x,
                                                  f16* __restrict__ xn) {
  int row = blockIdx.x * 4 + (threadIdx.x >> 6);
  int lane = threadIdx.x & 63;
  int id = ids[row];
  const float* er = emb + (size_t)id * Dn;
  float a = er[lane], b = er[lane + 64];
  float s1 = a + b, s2 = a * a + b * b;
  #pragma unroll
  for (int off = 32; off; off >>= 1) {
    s1 += __shfl_xor(s1, off);
    s2 += __shfl_xor(s2, off);
  }
  float mu = s1 * (1.f / 128.f);
  float var = s2 * (1.f / 128.f) - mu * mu;
  float rs = rsqrtf(var + 1e-5f);
  float* xr = x + (size_t)row * Dn;
  xr[lane] = a; xr[lane + 64] = b;
  f16* xo = xn + (size_t)row * Dn;
  xo[lane]      = (f16)((a - mu) * rs * lw[lane] + lb[lane]);
  xo[lane + 64] = (f16)((b - mu) * rs * lw[lane + 64] + lb[lane + 64]);
}

// ---------------- convert W (both layers) to f16 and R to transposed f16 ----------------
__global__ __launch_bounds__(256) void k_convert(const float* __restrict__ Wg,
                                                 const float* __restrict__ Rg,
                                                 f16* __restrict__ Wh,
                                                 f16* __restrict__ RT) {
  int i = blockIdx.x * 256 + threadIdx.x;
  const int nW = 2 * Cn * Dn;  // 131072
  if (i < nW) {
    Wh[i] = (f16)Wg[i];
  } else {
    int j = i - nW;  // 32768 = 2*4*4*32*32
    int dd = j & 31;
    int e  = (j >> 5) & 31;
    int hh = (j >> 10) & 3;
    int g  = (j >> 12) & 3;
    int l  = j >> 14;
    RT[j] = (f16)Rg[((((l * 4 + g) * 4 + hh) * 32 + dd) * 32) + e];
  }
}

// ---------------- layernorm per row (layer 1), fp32 -> f16 ----------------
__global__ __launch_bounds__(256) void k_ln(const float* __restrict__ x,
                                            const float* __restrict__ lw,
                                            const float* __restrict__ lb,
                                            f16* __restrict__ xn) {
  int row = blockIdx.x * 4 + (threadIdx.x >> 6);
  int lane = threadIdx.x & 63;
  const float* xr = x + (size_t)row * Dn;
  float a = xr[lane], b = xr[lane + 64];
  float s1 = a + b, s2 = a * a + b * b;
  #pragma unroll
  for (int off = 32; off; off >>= 1) {
    s1 += __shfl_xor(s1, off);
    s2 += __shfl_xor(s2, off);
  }
  float mu = s1 * (1.f / 128.f);
  float var = s2 * (1.f / 128.f) - mu * mu;
  float rs = rsqrtf(var + 1e-5f);
  f16* xo = xn + (size_t)row * Dn;
  xo[lane]      = (f16)((a - mu) * rs * lw[lane] + lb[lane]);
  xo[lane + 64] = (f16)((b - mu) * rs * lw[lane + 64] + lb[lane + 64]);
}

// ---------------- GEMM: preP[m][d] = packed {i,f,z,o} f16, m = b*L+t ----------------
// block = 256 thr (4 waves). Tile M=64 (wave=16 rows), N=512 (full). grid = 1024.
// Gate packing: col = i*16+l16; gate g = i>>3, d = (i&7)*16+l16 -> gates are
// fragments {i7, i7+8, i7+16, i7+24} of the SAME lane -> pack in-register.
__global__ __launch_bounds__(256) void k_gemm(const f16* __restrict__ xn,
                                              const f16* __restrict__ Wh,
                                              const float* __restrict__ bias,
                                              uint2* __restrict__ preP) {
  int w = threadIdx.x >> 6;
  int lane = threadIdx.x & 63;
  int l16 = lane & 15, quad = lane >> 4;
  int m0 = blockIdx.x * 64 + w * 16;

  float bv[32];
  #pragma unroll
  for (int i = 0; i < 32; ++i) bv[i] = bias[i * 16 + l16];

  f16x8 a[4];
  const f16* arow = xn + (size_t)(m0 + l16) * Dn + quad * 8;
  #pragma unroll
  for (int kk = 0; kk < 4; ++kk) a[kk] = *(const f16x8*)(arow + kk * 32);

  f32x4 acc[32] = {};
  const f16* bbase = Wh + (size_t)l16 * Dn + quad * 8;
  #pragma unroll
  for (int kk = 0; kk < 4; ++kk) {
    #pragma unroll
    for (int i = 0; i < 32; ++i) {
      f16x8 bf = *(const f16x8*)(bbase + (size_t)i * 16 * Dn + kk * 32);
      acc[i] = __builtin_amdgcn_mfma_f32_16x16x32_f16(a[kk], bf, acc[i], 0, 0, 0);
    }
  }
  #pragma unroll
  for (int r = 0; r < 4; ++r) {
    int m = m0 + quad * 4 + r;
    #pragma unroll
    for (int i7 = 0; i7 < 8; ++i7) {
      uint2 v;
      v.x = pk2(acc[i7][r]      + bv[i7],      acc[i7 + 8][r]  + bv[i7 + 8]);
      v.y = pk2(acc[i7 + 16][r] + bv[i7 + 16], acc[i7 + 24][r] + bv[i7 + 24]);
      preP[(size_t)m * Dn + i7 * 16 + l16] = v;
    }
  }
}

// ---------------- fused scan: barrier-free, deep register prefetch ----------------
// 256 blocks x 256 threads; block = 2 seqs, wave = half a seq (2 head groups).
// LAST=1: accumulate mean-pool instead of writing x.
template<int LAST>
__global__ __launch_bounds__(256) void k_scan(const uint2* __restrict__ preP,
                                              const f16* __restrict__ RT,
                                              const float* __restrict__ gnw,
                                              const float* __restrict__ xin,
                                              float* __restrict__ xout,
                                              float* __restrict__ pooled) {
  const int w = threadIdx.x >> 6;       // wave 0..3
  const int lane = threadIdx.x & 63;
  const int s = w >> 1;                 // seq within block
  const int b = blockIdx.x * 2 + s;
  const int d = ((w & 1) << 6) + lane;  // element 0..127 of this seq
  const int head = d >> 5;
  const int e = d & 31;
  const int half = lane >> 5;

  __shared__ __align__(16) f16 hsh[4][64];   // per-wave h exchange

  uint rr[4][16];
  const uint* RT32 = (const uint*)RT;
  #pragma unroll
  for (int g = 0; g < 4; ++g) {
    const uint* p = RT32 + ((g * 4 + head) * 32 + e) * 16;
    #pragma unroll
    for (int j = 0; j < 16; ++j) rr[g][j] = p[j];
  }
  const float gw = gnw[d];
  hsh[w][lane] = (f16)0.f;   // wave-local, DS in-order

  const uint2* pp = preP + (size_t)b * Ln * Dn + d;   // + t*Dn
  const float* xp = xin + (size_t)b * Ln * Dn + d;
  float* xo = xout + (size_t)b * Ln * Dn + d;

  // 4-deep raw-bits prefetch pipeline: loads issued 4 steps before use,
  // conversion (the first USE) happens at consume time.
  uint2 pb[4]; float xb[4];
  #pragma unroll
  for (int k = 0; k < 4; ++k) { pb[k] = pp[(size_t)k * Dn]; xb[k] = xp[(size_t)k * Dn]; }

  float cc = 0.f, nc = 0.f, mc = 0.f, psum = 0.f;

  #pragma unroll 1
  for (int t = 0; t < Ln; t += 4) {
    #pragma unroll
    for (int k = 0; k < 4; ++k) {
      uint2 pc = pb[k]; float xc = xb[k];
      int tl = t + k + 4;
      if (tl < Ln) {
        pb[k] = pp[(size_t)tl * Dn];
        xb[k] = xp[(size_t)tl * Dn];
      }

      // h(t-1) broadcast for my head group
      uint hu[16];
      {
        const uint4* hq = (const uint4*)(((const uint*)&hsh[w][0]) + half * 16);
        uint4 q0 = hq[0], q1 = hq[1], q2 = hq[2], q3 = hq[3];
        hu[0]=q0.x; hu[1]=q0.y; hu[2]=q0.z; hu[3]=q0.w;
        hu[4]=q1.x; hu[5]=q1.y; hu[6]=q1.z; hu[7]=q1.w;
        hu[8]=q2.x; hu[9]=q2.y; hu[10]=q2.z; hu[11]=q2.w;
        hu[12]=q3.x; hu[13]=q3.y; hu[14]=q3.z; hu[15]=q3.w;
      }
      float a0 = 0.f, a1 = 0.f, a2 = 0.f, a3 = 0.f;
      #pragma unroll
      for (int j = 0; j < 16; ++j) {
        a0 = fdot2f(hu[j], rr[0][j], a0);
        a1 = fdot2f(hu[j], rr[1][j], a1);
        a2 = fdot2f(hu[j], rr[2][j], a2);
        a3 = fdot2f(hu[j], rr[3][j], a3);
      }
      f16x2 lo = __builtin_bit_cast(f16x2, pc.x);
      f16x2 hi = __builtin_bit_cast(f16x2, pc.y);
      float it = (float)lo[0] + a0, ft = (float)lo[1] + a1;
      float zt = (float)hi[0] + a2, ot = (float)hi[1] + a3;

      float mn = fmaxf(ft + mc, it);
      float iv = __expf(it - mn);
      float fv = __expf(ft + mc - mn);
      float zc = fminf(fmaxf(zt, -15.f), 15.f);
      float ez = __expf(2.f * zc);
      float tz = (ez - 1.f) * __builtin_amdgcn_rcpf(ez + 1.f);
      float cn = fv * cc + iv * tz;
      float nn = fv * nc + iv;
      float sg = __builtin_amdgcn_rcpf(1.f + __expf(-ot));
      float hn = sg * cn * __builtin_amdgcn_rcpf(nn);
      cc = cn; nc = nn; mc = mn;

      hsh[w][lane] = (f16)hn;   // next-step exchange (wave-local)

      // groupnorm over 32-lane head group + residual
      float s1 = hn, s2 = hn * hn;
      #pragma unroll
      for (int off = 16; off; off >>= 1) {
        s1 += __shfl_xor(s1, off);
        s2 += __shfl_xor(s2, off);
      }
      float mu = s1 * (1.f / 32.f);
      float va = s2 * (1.f / 32.f) - mu * mu;
      float ov = xc + (hn - mu) * rsqrtf(va + 1e-5f) * gw;
      if (LAST) psum += ov;
      else      xo[(size_t)(t + k) * Dn] = ov;
    }
  }
  if (LAST) pooled[b * Dn + d] = psum * (1.f / 128.f);
}

// ---------------- head: MLP on pooled [512][128] ----------------
__global__ __launch_bounds__(64) void k_head(const float* __restrict__ pooled,
                                             const float* __restrict__ w1,
                                             const float* __restrict__ b1,
                                             const float* __restrict__ w2,
                                             const float* __restrict__ b2,
                                             float* __restrict__ out) {
  int b = blockIdx.x;
  int tid = threadIdx.x;  // 64
  __shared__ float pool[128];
  __shared__ float hid[64];
  pool[tid]      = pooled[b * Dn + tid];
  pool[tid + 64] = pooled[b * Dn + tid + 64];
  __syncthreads();
  {
    float a = b1[tid];
    const float* wr = w1 + (size_t)tid * Dn;
    #pragma unroll 4
    for (int dd = 0; dd < Dn; ++dd) a += pool[dd] * wr[dd];
    hid[tid] = fmaxf(a, 0.f);
  }
  __syncthreads();
  if (tid < 2) {
    float a = b2[tid];
    const float* wr = w2 + tid * 64;
    #pragma unroll 4
    for (int j = 0; j < 64; ++j) a += hid[j] * wr[j];
    out[b * 2 + tid] = a;
  }
}

extern "C" void kernel_launch(void* const* d_in, const int* in_sizes, int n_in,
                              void* d_out, int out_size, void* d_ws, size_t ws_size,
                              hipStream_t stream) {
  const int*   ids  = (const int*)d_in[0];
  const float* emb  = (const float*)d_in[1];
  const float* ln_w = (const float*)d_in[2];
  const float* ln_b = (const float*)d_in[3];
  const float* Wg   = (const float*)d_in[4];
  const float* Rg   = (const float*)d_in[5];
  const float* bg   = (const float*)d_in[6];
  const float* gn_w = (const float*)d_in[7];
  const float* w1   = (const float*)d_in[8];
  const float* b1   = (const float*)d_in[9];
  const float* w2   = (const float*)d_in[10];
  const float* b2   = (const float*)d_in[11];
  float* out = (float*)d_out;

  char* ws = (char*)d_ws;
  float* x     = (float*)ws;                                   // 33,554,432 B
  f16*   xn    = (f16*)(ws + 33554432);                        // 16,777,216 B
  uint2* preP  = (uint2*)(ws + 33554432 + 16777216);           // 67,108,864 B
  f16*   Wh    = (f16*)(ws + 117440512);                       //    262,144 B
  f16*   RT    = (f16*)(ws + 117440512 + 262144);              //     65,536 B
  float* pooled= (float*)(ws + 117440512 + 262144 + 65536);    //    262,144 B

  k_embed_ln<<<16384, 256, 0, stream>>>(ids, emb, ln_w, ln_b, x, xn);
  k_convert<<<640, 256, 0, stream>>>(Wg, Rg, Wh, RT);

  // layer 0
  k_gemm<<<1024, 256, 0, stream>>>(xn, Wh, bg, preP);
  k_scan<0><<<256, 256, 0, stream>>>(preP, RT, gn_w, x, x, nullptr);
  // layer 1
  k_ln<<<16384, 256, 0, stream>>>(x, ln_w + Dn, ln_b + Dn, xn);
  k_gemm<<<1024, 256, 0, stream>>>(xn, Wh + (size_t)Cn * Dn, bg + Cn, preP);
  k_scan<1><<<256, 256, 0, stream>>>(preP, RT + 16384, gn_w + Dn, x, nullptr, pooled);

  k_head<<<512, 64, 0, stream>>>(pooled, w1, b1, w2, b2, out);
}

// Round 5
// 351.278 us; speedup vs baseline: 1.3931x; 1.3931x over previous
//
#include <hip/hip_runtime.h>

typedef _Float16 f16;
typedef unsigned int uint;
typedef f16 f16x2 __attribute__((ext_vector_type(2)));
typedef f16 f16x8 __attribute__((ext_vector_type(8)));
typedef __fp16 h16x2 __attribute__((ext_vector_type(2)));
typedef float f32x4 __attribute__((ext_vector_type(4)));

#define Bn 512
#define Ln 128
#define Dn 128
#define Cn 512   // 4 gates * D

__device__ __forceinline__ float fdot2f(uint a, uint b, float c) {
#if __has_builtin(__builtin_amdgcn_fdot2)
  return __builtin_amdgcn_fdot2(__builtin_bit_cast(f16x2, a),
                                __builtin_bit_cast(f16x2, b), c, false);
#else
  f16x2 av = __builtin_bit_cast(f16x2, a), bv = __builtin_bit_cast(f16x2, b);
  return c + (float)av[0] * (float)bv[0] + (float)av[1] * (float)bv[1];
#endif
}

__device__ __forceinline__ uint pk2(float a, float b) {
#if __has_builtin(__builtin_amdgcn_cvt_pkrtz)
  h16x2 v = __builtin_amdgcn_cvt_pkrtz(a, b);
  return __builtin_bit_cast(uint, v);
#else
  f16x2 v; v[0] = (f16)a; v[1] = (f16)b;
  return __builtin_bit_cast(uint, v);
#endif
}

// ---------------- fused embedding gather + layernorm(layer0) ----------------
__global__ __launch_bounds__(256) void k_embed_ln(const int* __restrict__ ids,
                                                  const float* __restrict__ emb,
                                                  const float* __restrict__ lw,
                                                  const float* __restrict__ lb,
                                                  float* __restrict__ x,
                                                  f16* __restrict__ xn) {
  int row = blockIdx.x * 4 + (threadIdx.x >> 6);
  int lane = threadIdx.x & 63;
  int id = ids[row];
  const float* er = emb + (size_t)id * Dn;
  float a = er[lane], b = er[lane + 64];
  float s1 = a + b, s2 = a * a + b * b;
  #pragma unroll
  for (int off = 32; off; off >>= 1) {
    s1 += __shfl_xor(s1, off);
    s2 += __shfl_xor(s2, off);
  }
  float mu = s1 * (1.f / 128.f);
  float var = s2 * (1.f / 128.f) - mu * mu;
  float rs = rsqrtf(var + 1e-5f);
  float* xr = x + (size_t)row * Dn;
  xr[lane] = a; xr[lane + 64] = b;
  f16* xo = xn + (size_t)row * Dn;
  xo[lane]      = (f16)((a - mu) * rs * lw[lane] + lb[lane]);
  xo[lane + 64] = (f16)((b - mu) * rs * lw[lane + 64] + lb[lane + 64]);
}

// ---------------- convert: W -> MFMA-fragment-ordered f16 (WhF), R -> transposed f16 ----------------
// WhF per layer: frag (kk,i) at offset ((kk*32+i)*64 + lane)*8 + j  (f16 units)
//   value = Wg[l][c][d], c = i*16 + (lane&15), d = kk*32 + (lane>>4)*8 + j
__global__ __launch_bounds__(256) void k_convert(const float* __restrict__ Wg,
                                                 const float* __restrict__ Rg,
                                                 f16* __restrict__ WhF,
                                                 f16* __restrict__ RT) {
  int i = blockIdx.x * 256 + threadIdx.x;
  const int nWfrag = 2 * 4 * 32 * 64;   // 16384 groups of 8 f16
  if (i < nWfrag) {
    int lane = i & 63;
    int ii   = (i >> 6) & 31;
    int kk   = (i >> 11) & 3;
    int l    = i >> 13;
    int c = ii * 16 + (lane & 15);
    int d = kk * 32 + ((lane >> 4) << 3);
    const float* src = Wg + ((size_t)(l * 512 + c) * 128 + d);
    f16* dst = WhF + (size_t)i * 8;
    #pragma unroll
    for (int j = 0; j < 8; ++j) dst[j] = (f16)src[j];
  } else {
    int j = i - nWfrag;  // 32768 = 2*4*4*32*32
    if (j < 32768) {
      int dd = j & 31;
      int e  = (j >> 5) & 31;
      int hh = (j >> 10) & 3;
      int g  = (j >> 12) & 3;
      int l  = j >> 14;
      RT[j] = (f16)Rg[((((l * 4 + g) * 4 + hh) * 32 + dd) * 32) + e];
    }
  }
}

// ---------------- layernorm per row (layer 1), fp32 -> f16 ----------------
__global__ __launch_bounds__(256) void k_ln(const float* __restrict__ x,
                                            const float* __restrict__ lw,
                                            const float* __restrict__ lb,
                                            f16* __restrict__ xn) {
  int row = blockIdx.x * 4 + (threadIdx.x >> 6);
  int lane = threadIdx.x & 63;
  const float* xr = x + (size_t)row * Dn;
  float a = xr[lane], b = xr[lane + 64];
  float s1 = a + b, s2 = a * a + b * b;
  #pragma unroll
  for (int off = 32; off; off >>= 1) {
    s1 += __shfl_xor(s1, off);
    s2 += __shfl_xor(s2, off);
  }
  float mu = s1 * (1.f / 128.f);
  float var = s2 * (1.f / 128.f) - mu * mu;
  float rs = rsqrtf(var + 1e-5f);
  f16* xo = xn + (size_t)row * Dn;
  xo[lane]      = (f16)((a - mu) * rs * lw[lane] + lb[lane]);
  xo[lane + 64] = (f16)((b - mu) * rs * lw[lane + 64] + lb[lane + 64]);
}

// ---------------- GEMM: preP[m][d] = packed {i,f,z,o} f16, m = b*L+t ----------------
// B fragments come from WhF in fragment order: each load is one contiguous
// 1KB wave-load (lane*16B) -> no TA segment scatter.
__global__ __launch_bounds__(256) void k_gemm(const f16* __restrict__ xn,
                                              const f16* __restrict__ WhF,
                                              const float* __restrict__ bias,
                                              uint2* __restrict__ preP) {
  int w = threadIdx.x >> 6;
  int lane = threadIdx.x & 63;
  int l16 = lane & 15, quad = lane >> 4;
  int m0 = blockIdx.x * 64 + w * 16;

  float bv[32];
  #pragma unroll
  for (int i = 0; i < 32; ++i) bv[i] = bias[i * 16 + l16];

  f16x8 a[4];
  const f16* arow = xn + (size_t)(m0 + l16) * Dn + quad * 8;
  #pragma unroll
  for (int kk = 0; kk < 4; ++kk) a[kk] = *(const f16x8*)(arow + kk * 32);

  f32x4 acc[32] = {};
  const f16* bbase = WhF + (size_t)lane * 8;
  #pragma unroll
  for (int kk = 0; kk < 4; ++kk) {
    #pragma unroll
    for (int i = 0; i < 32; ++i) {
      f16x8 bf = *(const f16x8*)(bbase + (size_t)(kk * 32 + i) * 512);
      acc[i] = __builtin_amdgcn_mfma_f32_16x16x32_f16(a[kk], bf, acc[i], 0, 0, 0);
    }
  }
  #pragma unroll
  for (int r = 0; r < 4; ++r) {
    int m = m0 + quad * 4 + r;
    #pragma unroll
    for (int i7 = 0; i7 < 8; ++i7) {
      uint2 v;
      v.x = pk2(acc[i7][r]      + bv[i7],      acc[i7 + 8][r]  + bv[i7 + 8]);
      v.y = pk2(acc[i7 + 16][r] + bv[i7 + 16], acc[i7 + 24][r] + bv[i7 + 24]);
      preP[(size_t)m * Dn + i7 * 16 + l16] = v;
    }
  }
}

// ---------------- fused scan: barrier-free, 8-deep register prefetch ----------------
template<int LAST>
__global__ __launch_bounds__(256) void k_scan(const uint2* __restrict__ preP,
                                              const f16* __restrict__ RT,
                                              const float* __restrict__ gnw,
                                              const float* __restrict__ xin,
                                              float* __restrict__ xout,
                                              float* __restrict__ pooled) {
  const int w = threadIdx.x >> 6;       // wave 0..3
  const int lane = threadIdx.x & 63;
  const int s = w >> 1;                 // seq within block
  const int b = blockIdx.x * 2 + s;
  const int d = ((w & 1) << 6) + lane;  // element 0..127 of this seq
  const int head = d >> 5;
  const int e = d & 31;
  const int half = lane >> 5;

  __shared__ __align__(16) f16 hsh[4][64];   // per-wave h exchange

  uint rr[4][16];
  const uint* RT32 = (const uint*)RT;
  #pragma unroll
  for (int g = 0; g < 4; ++g) {
    const uint* p = RT32 + ((g * 4 + head) * 32 + e) * 16;
    #pragma unroll
    for (int j = 0; j < 16; ++j) rr[g][j] = p[j];
  }
  const float gw = gnw[d];
  hsh[w][lane] = (f16)0.f;   // wave-local, DS in-order

  const uint2* pp = preP + (size_t)b * Ln * Dn + d;   // + t*Dn
  const float* xp = xin + (size_t)b * Ln * Dn + d;
  float* xo = xout + (size_t)b * Ln * Dn + d;

  // 8-deep raw-bits prefetch pipeline
  uint2 pb[8]; float xb[8];
  #pragma unroll
  for (int k = 0; k < 8; ++k) { pb[k] = pp[(size_t)k * Dn]; xb[k] = xp[(size_t)k * Dn]; }

  float cc = 0.f, nc = 0.f, mc = 0.f, psum = 0.f;

  #pragma unroll 1
  for (int t = 0; t < Ln; t += 8) {
    #pragma unroll
    for (int k = 0; k < 8; ++k) {
      uint2 pc = pb[k]; float xc = xb[k];
      int tl = t + k + 8;
      if (tl < Ln) {
        pb[k] = pp[(size_t)tl * Dn];
        xb[k] = xp[(size_t)tl * Dn];
      }

      // h(t-1) broadcast for my head group
      uint hu[16];
      {
        const uint4* hq = (const uint4*)(((const uint*)&hsh[w][0]) + half * 16);
        uint4 q0 = hq[0], q1 = hq[1], q2 = hq[2], q3 = hq[3];
        hu[0]=q0.x; hu[1]=q0.y; hu[2]=q0.z; hu[3]=q0.w;
        hu[4]=q1.x; hu[5]=q1.y; hu[6]=q1.z; hu[7]=q1.w;
        hu[8]=q2.x; hu[9]=q2.y; hu[10]=q2.z; hu[11]=q2.w;
        hu[12]=q3.x; hu[13]=q3.y; hu[14]=q3.z; hu[15]=q3.w;
      }
      float a0 = 0.f, a1 = 0.f, a2 = 0.f, a3 = 0.f;
      #pragma unroll
      for (int j = 0; j < 16; ++j) {
        a0 = fdot2f(hu[j], rr[0][j], a0);
        a1 = fdot2f(hu[j], rr[1][j], a1);
        a2 = fdot2f(hu[j], rr[2][j], a2);
        a3 = fdot2f(hu[j], rr[3][j], a3);
      }
      f16x2 lo = __builtin_bit_cast(f16x2, pc.x);
      f16x2 hi = __builtin_bit_cast(f16x2, pc.y);
      float it = (float)lo[0] + a0, ft = (float)lo[1] + a1;
      float zt = (float)hi[0] + a2, ot = (float)hi[1] + a3;

      float mn = fmaxf(ft + mc, it);
      float iv = __expf(it - mn);
      float fv = __expf(ft + mc - mn);
      float zc = fminf(fmaxf(zt, -15.f), 15.f);
      float ez = __expf(2.f * zc);
      float tz = (ez - 1.f) * __builtin_amdgcn_rcpf(ez + 1.f);
      float cn = fv * cc + iv * tz;
      float nn = fv * nc + iv;
      float sg = __builtin_amdgcn_rcpf(1.f + __expf(-ot));
      float hn = sg * cn * __builtin_amdgcn_rcpf(nn);
      cc = cn; nc = nn; mc = mn;

      hsh[w][lane] = (f16)hn;   // next-step exchange (wave-local)

      // groupnorm over 32-lane head group + residual
      float s1 = hn, s2 = hn * hn;
      #pragma unroll
      for (int off = 16; off; off >>= 1) {
        s1 += __shfl_xor(s1, off);
        s2 += __shfl_xor(s2, off);
      }
      float mu = s1 * (1.f / 32.f);
      float va = s2 * (1.f / 32.f) - mu * mu;
      float ov = xc + (hn - mu) * rsqrtf(va + 1e-5f) * gw;
      if (LAST) psum += ov;
      else      xo[(size_t)(t + k) * Dn] = ov;
    }
  }
  if (LAST) pooled[b * Dn + d] = psum * (1.f / 128.f);
}

// ---------------- head: MLP on pooled [512][128] ----------------
__global__ __launch_bounds__(64) void k_head(const float* __restrict__ pooled,
                                             const float* __restrict__ w1,
                                             const float* __restrict__ b1,
                                             const float* __restrict__ w2,
                                             const float* __restrict__ b2,
                                             float* __restrict__ out) {
  int b = blockIdx.x;
  int tid = threadIdx.x;  // 64
  __shared__ float pool[128];
  __shared__ float hid[64];
  pool[tid]      = pooled[b * Dn + tid];
  pool[tid + 64] = pooled[b * Dn + tid + 64];
  __syncthreads();
  {
    float a = b1[tid];
    const float* wr = w1 + (size_t)tid * Dn;
    #pragma unroll 4
    for (int dd = 0; dd < Dn; ++dd) a += pool[dd] * wr[dd];
    hid[tid] = fmaxf(a, 0.f);
  }
  __syncthreads();
  if (tid < 2) {
    float a = b2[tid];
    const float* wr = w2 + tid * 64;
    #pragma unroll 4
    for (int j = 0; j < 64; ++j) a += hid[j] * wr[j];
    out[b * 2 + tid] = a;
  }
}

extern "C" void kernel_launch(void* const* d_in, const int* in_sizes, int n_in,
                              void* d_out, int out_size, void* d_ws, size_t ws_size,
                              hipStream_t stream) {
  const int*   ids  = (const int*)d_in[0];
  const float* emb  = (const float*)d_in[1];
  const float* ln_w = (const float*)d_in[2];
  const float* ln_b = (const float*)d_in[3];
  const float* Wg   = (const float*)d_in[4];
  const float* Rg   = (const float*)d_in[5];
  const float* bg   = (const float*)d_in[6];
  const float* gn_w = (const float*)d_in[7];
  const float* w1   = (const float*)d_in[8];
  const float* b1   = (const float*)d_in[9];
  const float* w2   = (const float*)d_in[10];
  const float* b2   = (const float*)d_in[11];
  float* out = (float*)d_out;

  char* ws = (char*)d_ws;
  float* x     = (float*)ws;                                   // 33,554,432 B
  f16*   xn    = (f16*)(ws + 33554432);                        // 16,777,216 B
  uint2* preP  = (uint2*)(ws + 33554432 + 16777216);           // 67,108,864 B
  f16*   WhF   = (f16*)(ws + 117440512);                       //    262,144 B
  f16*   RT    = (f16*)(ws + 117440512 + 262144);              //     65,536 B
  float* pooled= (float*)(ws + 117440512 + 262144 + 65536);    //    262,144 B

  k_embed_ln<<<16384, 256, 0, stream>>>(ids, emb, ln_w, ln_b, x, xn);
  k_convert<<<192, 256, 0, stream>>>(Wg, Rg, WhF, RT);

  // layer 0
  k_gemm<<<1024, 256, 0, stream>>>(xn, WhF, bg, preP);
  k_scan<0><<<256, 256, 0, stream>>>(preP, RT, gn_w, x, x, nullptr);
  // layer 1
  k_ln<<<16384, 256, 0, stream>>>(x, ln_w + Dn, ln_b + Dn, xn);
  k_gemm<<<1024, 256, 0, stream>>>(xn, WhF + 65536, bg + Cn, preP);
  k_scan<1><<<256, 256, 0, stream>>>(preP, RT + 16384, gn_w + Dn, x, nullptr, pooled);

  k_head<<<512, 64, 0, stream>>>(pooled, w1, b1, w2, b2, out);
}

// Round 6
// 327.086 us; speedup vs baseline: 1.4961x; 1.0740x over previous
//
#include <hip/hip_runtime.h>

typedef _Float16 f16;
typedef unsigned int uint;
typedef f16 f16x2 __attribute__((ext_vector_type(2)));
typedef f16 f16x8 __attribute__((ext_vector_type(8)));
typedef __fp16 h16x2 __attribute__((ext_vector_type(2)));
typedef float f32x4 __attribute__((ext_vector_type(4)));

#define Bn 512
#define Ln 128
#define Dn 128
#define Cn 512   // 4 gates * D

__device__ __forceinline__ float fdot2f(uint a, uint b, float c) {
#if __has_builtin(__builtin_amdgcn_fdot2)
  return __builtin_amdgcn_fdot2(__builtin_bit_cast(f16x2, a),
                                __builtin_bit_cast(f16x2, b), c, false);
#else
  f16x2 av = __builtin_bit_cast(f16x2, a), bv = __builtin_bit_cast(f16x2, b);
  return c + (float)av[0] * (float)bv[0] + (float)av[1] * (float)bv[1];
#endif
}

__device__ __forceinline__ uint pk2(float a, float b) {
#if __has_builtin(__builtin_amdgcn_cvt_pkrtz)
  h16x2 v = __builtin_amdgcn_cvt_pkrtz(a, b);
  return __builtin_bit_cast(uint, v);
#else
  f16x2 v; v[0] = (f16)a; v[1] = (f16)b;
  return __builtin_bit_cast(uint, v);
#endif
}

// ---------------- fused embedding gather + layernorm(layer0) ----------------
__global__ __launch_bounds__(256) void k_embed_ln(const int* __restrict__ ids,
                                                  const float* __restrict__ emb,
                                                  const float* __restrict__ lw,
                                                  const float* __restrict__ lb,
                                                  float* __restrict__ x,
                                                  f16* __restrict__ xn) {
  int row = blockIdx.x * 4 + (threadIdx.x >> 6);
  int lane = threadIdx.x & 63;
  int id = ids[row];
  const float* er = emb + (size_t)id * Dn;
  float a = er[lane], b = er[lane + 64];
  float s1 = a + b, s2 = a * a + b * b;
  #pragma unroll
  for (int off = 32; off; off >>= 1) {
    s1 += __shfl_xor(s1, off);
    s2 += __shfl_xor(s2, off);
  }
  float mu = s1 * (1.f / 128.f);
  float var = s2 * (1.f / 128.f) - mu * mu;
  float rs = rsqrtf(var + 1e-5f);
  float* xr = x + (size_t)row * Dn;
  xr[lane] = a; xr[lane + 64] = b;
  f16* xo = xn + (size_t)row * Dn;
  xo[lane]      = (f16)((a - mu) * rs * lw[lane] + lb[lane]);
  xo[lane + 64] = (f16)((b - mu) * rs * lw[lane + 64] + lb[lane + 64]);
}

// ---------------- convert: W -> MFMA-fragment-ordered f16 (WhF), R -> transposed f16 ----------------
__global__ __launch_bounds__(256) void k_convert(const float* __restrict__ Wg,
                                                 const float* __restrict__ Rg,
                                                 f16* __restrict__ WhF,
                                                 f16* __restrict__ RT) {
  int i = blockIdx.x * 256 + threadIdx.x;
  const int nWfrag = 2 * 4 * 32 * 64;   // 16384 groups of 8 f16
  if (i < nWfrag) {
    int lane = i & 63;
    int ii   = (i >> 6) & 31;
    int kk   = (i >> 11) & 3;
    int l    = i >> 13;
    int c = ii * 16 + (lane & 15);
    int d = kk * 32 + ((lane >> 4) << 3);
    const float* src = Wg + ((size_t)(l * 512 + c) * 128 + d);
    f16* dst = WhF + (size_t)i * 8;
    #pragma unroll
    for (int j = 0; j < 8; ++j) dst[j] = (f16)src[j];
  } else {
    int j = i - nWfrag;  // 32768 = 2*4*4*32*32
    if (j < 32768) {
      int dd = j & 31;
      int e  = (j >> 5) & 31;
      int hh = (j >> 10) & 3;
      int g  = (j >> 12) & 3;
      int l  = j >> 14;
      RT[j] = (f16)Rg[((((l * 4 + g) * 4 + hh) * 32 + dd) * 32) + e];
    }
  }
}

// ---------------- layernorm per row (layer 1), fp32 -> f16 ----------------
__global__ __launch_bounds__(256) void k_ln(const float* __restrict__ x,
                                            const float* __restrict__ lw,
                                            const float* __restrict__ lb,
                                            f16* __restrict__ xn) {
  int row = blockIdx.x * 4 + (threadIdx.x >> 6);
  int lane = threadIdx.x & 63;
  const float* xr = x + (size_t)row * Dn;
  float a = xr[lane], b = xr[lane + 64];
  float s1 = a + b, s2 = a * a + b * b;
  #pragma unroll
  for (int off = 32; off; off >>= 1) {
    s1 += __shfl_xor(s1, off);
    s2 += __shfl_xor(s2, off);
  }
  float mu = s1 * (1.f / 128.f);
  float var = s2 * (1.f / 128.f) - mu * mu;
  float rs = rsqrtf(var + 1e-5f);
  f16* xo = xn + (size_t)row * Dn;
  xo[lane]      = (f16)((a - mu) * rs * lw[lane] + lb[lane]);
  xo[lane + 64] = (f16)((b - mu) * rs * lw[lane + 64] + lb[lane + 64]);
}

// ---------------- GEMM: preP[m][d] = packed {i,f,z,o} f16, m = b*L+t ----------------
__global__ __launch_bounds__(256) void k_gemm(const f16* __restrict__ xn,
                                              const f16* __restrict__ WhF,
                                              const float* __restrict__ bias,
                                              uint2* __restrict__ preP) {
  int w = threadIdx.x >> 6;
  int lane = threadIdx.x & 63;
  int l16 = lane & 15, quad = lane >> 4;
  int m0 = blockIdx.x * 64 + w * 16;

  float bv[32];
  #pragma unroll
  for (int i = 0; i < 32; ++i) bv[i] = bias[i * 16 + l16];

  f16x8 a[4];
  const f16* arow = xn + (size_t)(m0 + l16) * Dn + quad * 8;
  #pragma unroll
  for (int kk = 0; kk < 4; ++kk) a[kk] = *(const f16x8*)(arow + kk * 32);

  f32x4 acc[32] = {};
  const f16* bbase = WhF + (size_t)lane * 8;
  #pragma unroll
  for (int kk = 0; kk < 4; ++kk) {
    #pragma unroll
    for (int i = 0; i < 32; ++i) {
      f16x8 bf = *(const f16x8*)(bbase + (size_t)(kk * 32 + i) * 512);
      acc[i] = __builtin_amdgcn_mfma_f32_16x16x32_f16(a[kk], bf, acc[i], 0, 0, 0);
    }
  }
  #pragma unroll
  for (int r = 0; r < 4; ++r) {
    int m = m0 + quad * 4 + r;
    #pragma unroll
    for (int i7 = 0; i7 < 8; ++i7) {
      uint2 v;
      v.x = pk2(acc[i7][r]      + bv[i7],      acc[i7 + 8][r]  + bv[i7 + 8]);
      v.y = pk2(acc[i7 + 16][r] + bv[i7 + 16], acc[i7 + 24][r] + bv[i7 + 24]);
      preP[(size_t)m * Dn + i7 * 16 + l16] = v;
    }
  }
}

// ---------------- fused scan: shuffle-free deferred groupnorm ----------------
// Each wave owns 2 (seq,head) groups; h exchange is wave-local LDS (no barriers).
// GroupNorm of step t-1 is computed at step t IN-LANE from the hu broadcast
// (stats via v_dot2), eliminating all cross-lane shuffle latency.
template<int LAST>
__global__ __launch_bounds__(256, 1) void k_scan(const uint2* __restrict__ preP,
                                                 const f16* __restrict__ RT,
                                                 const float* __restrict__ gnw,
                                                 const float* __restrict__ xin,
                                                 float* __restrict__ xout,
                                                 float* __restrict__ pooled) {
  const int w = threadIdx.x >> 6;       // wave 0..3
  const int lane = threadIdx.x & 63;
  const int s = w >> 1;                 // seq within block
  const int b = blockIdx.x * 2 + s;
  const int d = ((w & 1) << 6) + lane;  // element 0..127 of this seq
  const int head = d >> 5;
  const int e = d & 31;
  const int half = lane >> 5;
  const uint one2 = 0x3C003C00u;        // f16 {1.0, 1.0}

  __shared__ __align__(16) f16 hsh[4][64];   // per-wave h exchange

  uint rr[4][16];
  const uint* RT32 = (const uint*)RT;
  #pragma unroll
  for (int g = 0; g < 4; ++g) {
    const uint* p = RT32 + ((g * 4 + head) * 32 + e) * 16;
    #pragma unroll
    for (int j = 0; j < 16; ++j) rr[g][j] = p[j];
  }
  const float gw = gnw[d];
  hsh[w][lane] = (f16)0.f;   // wave-local, DS in-order

  const uint2* pp = preP + (size_t)b * Ln * Dn + d;   // + t*Dn
  const float* xp = xin + (size_t)b * Ln * Dn + d;
  float* xo = xout + (size_t)b * Ln * Dn + d;

  // 8-deep raw-bits prefetch pipeline
  uint2 pb[8]; float xb[8];
  #pragma unroll
  for (int k = 0; k < 8; ++k) { pb[k] = pp[(size_t)k * Dn]; xb[k] = xp[(size_t)k * Dn]; }

  float cc = 0.f, nc = 0.f, mc = 0.f, psum = 0.f;
  float hprev = 0.f, xprev = 0.f;

  #pragma unroll 1
  for (int t = 0; t < Ln; t += 8) {
    #pragma unroll
    for (int k = 0; k < 8; ++k) {
      int tt = t + k;
      uint2 pc = pb[k]; float xc = xb[k];
      int tl = tt + 8;
      if (tl < Ln) {
        pb[k] = pp[(size_t)tl * Dn];
        xb[k] = xp[(size_t)tl * Dn];
      }

      // hu = h(tt-1) broadcast for my head group (4x ds_read_b128)
      uint hu[16];
      {
        const uint4* hq = (const uint4*)(((const uint*)&hsh[w][0]) + half * 16);
        uint4 q0 = hq[0], q1 = hq[1], q2 = hq[2], q3 = hq[3];
        hu[0]=q0.x; hu[1]=q0.y; hu[2]=q0.z; hu[3]=q0.w;
        hu[4]=q1.x; hu[5]=q1.y; hu[6]=q1.z; hu[7]=q1.w;
        hu[8]=q2.x; hu[9]=q2.y; hu[10]=q2.z; hu[11]=q2.w;
        hu[12]=q3.x; hu[13]=q3.y; hu[14]=q3.z; hu[15]=q3.w;
      }

      // deferred groupnorm of step tt-1: in-lane stats from hu (no shuffles)
      float s1 = 0.f, s2 = 0.f;
      #pragma unroll
      for (int j = 0; j < 16; ++j) {
        s1 = fdot2f(hu[j], one2, s1);
        s2 = fdot2f(hu[j], hu[j], s2);
      }
      {
        float mu = s1 * (1.f / 32.f);
        float va = s2 * (1.f / 32.f) - mu * mu;
        float ov = xprev + (hprev - mu) * rsqrtf(va + 1e-5f) * gw;
        if (tt > 0) {
          if (LAST) psum += ov;
          else      xo[(size_t)(tt - 1) * Dn] = ov;
        }
      }

      // recurrence dot products
      float a0 = 0.f, a1 = 0.f, a2 = 0.f, a3 = 0.f;
      #pragma unroll
      for (int j = 0; j < 16; ++j) {
        a0 = fdot2f(hu[j], rr[0][j], a0);
        a1 = fdot2f(hu[j], rr[1][j], a1);
        a2 = fdot2f(hu[j], rr[2][j], a2);
        a3 = fdot2f(hu[j], rr[3][j], a3);
      }
      f16x2 lo = __builtin_bit_cast(f16x2, pc.x);
      f16x2 hi = __builtin_bit_cast(f16x2, pc.y);
      float it = (float)lo[0] + a0, ft = (float)lo[1] + a1;
      float zt = (float)hi[0] + a2, ot = (float)hi[1] + a3;

      float mn = fmaxf(ft + mc, it);
      float iv = __expf(it - mn);
      float fv = __expf(ft + mc - mn);
      float zc = fminf(fmaxf(zt, -15.f), 15.f);
      float ez = __expf(2.f * zc);
      float tz = (ez - 1.f) * __builtin_amdgcn_rcpf(ez + 1.f);
      float cn = fv * cc + iv * tz;
      float nn = fv * nc + iv;
      float sg = __builtin_amdgcn_rcpf(1.f + __expf(-ot));
      float hn = sg * cn * __builtin_amdgcn_rcpf(nn);
      cc = cn; nc = nn; mc = mn;

      hsh[w][lane] = (f16)hn;   // next-step exchange (wave-local)
      hprev = hn; xprev = xc;
    }
  }

  // epilogue: groupnorm of step 127
  {
    uint hu[16];
    const uint4* hq = (const uint4*)(((const uint*)&hsh[w][0]) + half * 16);
    uint4 q0 = hq[0], q1 = hq[1], q2 = hq[2], q3 = hq[3];
    hu[0]=q0.x; hu[1]=q0.y; hu[2]=q0.z; hu[3]=q0.w;
    hu[4]=q1.x; hu[5]=q1.y; hu[6]=q1.z; hu[7]=q1.w;
    hu[8]=q2.x; hu[9]=q2.y; hu[10]=q2.z; hu[11]=q2.w;
    hu[12]=q3.x; hu[13]=q3.y; hu[14]=q3.z; hu[15]=q3.w;
    float s1 = 0.f, s2 = 0.f;
    #pragma unroll
    for (int j = 0; j < 16; ++j) {
      s1 = fdot2f(hu[j], one2, s1);
      s2 = fdot2f(hu[j], hu[j], s2);
    }
    float mu = s1 * (1.f / 32.f);
    float va = s2 * (1.f / 32.f) - mu * mu;
    float ov = xprev + (hprev - mu) * rsqrtf(va + 1e-5f) * gw;
    if (LAST) {
      psum += ov;
      pooled[b * Dn + d] = psum * (1.f / 128.f);
    } else {
      xo[(size_t)(Ln - 1) * Dn] = ov;
    }
  }
}

// ---------------- head: MLP on pooled [512][128] ----------------
__global__ __launch_bounds__(64) void k_head(const float* __restrict__ pooled,
                                             const float* __restrict__ w1,
                                             const float* __restrict__ b1,
                                             const float* __restrict__ w2,
                                             const float* __restrict__ b2,
                                             float* __restrict__ out) {
  int b = blockIdx.x;
  int tid = threadIdx.x;  // 64
  __shared__ float pool[128];
  __shared__ float hid[64];
  pool[tid]      = pooled[b * Dn + tid];
  pool[tid + 64] = pooled[b * Dn + tid + 64];
  __syncthreads();
  {
    float a = b1[tid];
    const float* wr = w1 + (size_t)tid * Dn;
    #pragma unroll 4
    for (int dd = 0; dd < Dn; ++dd) a += pool[dd] * wr[dd];
    hid[tid] = fmaxf(a, 0.f);
  }
  __syncthreads();
  if (tid < 2) {
    float a = b2[tid];
    const float* wr = w2 + tid * 64;
    #pragma unroll 4
    for (int j = 0; j < 64; ++j) a += hid[j] * wr[j];
    out[b * 2 + tid] = a;
  }
}

extern "C" void kernel_launch(void* const* d_in, const int* in_sizes, int n_in,
                              void* d_out, int out_size, void* d_ws, size_t ws_size,
                              hipStream_t stream) {
  const int*   ids  = (const int*)d_in[0];
  const float* emb  = (const float*)d_in[1];
  const float* ln_w = (const float*)d_in[2];
  const float* ln_b = (const float*)d_in[3];
  const float* Wg   = (const float*)d_in[4];
  const float* Rg   = (const float*)d_in[5];
  const float* bg   = (const float*)d_in[6];
  const float* gn_w = (const float*)d_in[7];
  const float* w1   = (const float*)d_in[8];
  const float* b1   = (const float*)d_in[9];
  const float* w2   = (const float*)d_in[10];
  const float* b2   = (const float*)d_in[11];
  float* out = (float*)d_out;

  char* ws = (char*)d_ws;
  float* x     = (float*)ws;                                   // 33,554,432 B
  f16*   xn    = (f16*)(ws + 33554432);                        // 16,777,216 B
  uint2* preP  = (uint2*)(ws + 33554432 + 16777216);           // 67,108,864 B
  f16*   WhF   = (f16*)(ws + 117440512);                       //    262,144 B
  f16*   RT    = (f16*)(ws + 117440512 + 262144);              //     65,536 B
  float* pooled= (float*)(ws + 117440512 + 262144 + 65536);    //    262,144 B

  k_embed_ln<<<16384, 256, 0, stream>>>(ids, emb, ln_w, ln_b, x, xn);
  k_convert<<<192, 256, 0, stream>>>(Wg, Rg, WhF, RT);

  // layer 0
  k_gemm<<<1024, 256, 0, stream>>>(xn, WhF, bg, preP);
  k_scan<0><<<256, 256, 0, stream>>>(preP, RT, gn_w, x, x, nullptr);
  // layer 1
  k_ln<<<16384, 256, 0, stream>>>(x, ln_w + Dn, ln_b + Dn, xn);
  k_gemm<<<1024, 256, 0, stream>>>(xn, WhF + 65536, bg + Cn, preP);
  k_scan<1><<<256, 256, 0, stream>>>(preP, RT + 16384, gn_w + Dn, x, nullptr, pooled);

  k_head<<<512, 64, 0, stream>>>(pooled, w1, b1, w2, b2, out);
}